// Round 1
// baseline (913.506 us; speedup 1.0000x reference)
//
#include <hip/hip_runtime.h>
#include <hip/hip_bf16.h>

// SDPA, attention materialized. B=2 H=16 S=2048 D=64, fp32 in/out.
// Round 3: barrier-free sdpa_main. K/V are L2-resident per-XCD (bid%8 swizzle
// pins all 32 q-tiles of a bh to one XCD: 4 bh x 512KB = 2MB < 4MB L2), so
// LDS staging + 2 barriers/tile was pure overhead (Common-mistake #7).
// Waves now load K/V MFMA fragments directly from global (L2 hit), V is
// register-prefetched per tile; only LDS left is the wave-private P transpose.

#define S_LEN 2048
#define D_DIM 64
#define LOG2E 1.44269504088896340736f

typedef __attribute__((ext_vector_type(8))) short bf16x8;
typedef __attribute__((ext_vector_type(4))) float f32x4;
typedef unsigned long long u64;

__device__ __forceinline__ unsigned int f2bs2(float x, float y) {
    union { __hip_bfloat162 h; unsigned int u; } u;
    u.h = __float22bfloat162_rn(make_float2(x, y));
    return u.u;
}
__device__ __forceinline__ short f2bs(float f) {
    union { __hip_bfloat16 h; short s; } u;
    u.h = __float2bfloat16(f);
    return u.s;
}
__device__ __forceinline__ bf16x8 cvt8(float4 a, float4 b) {
    union { bf16x8 v; unsigned int w[4]; } u;
    u.w[0] = f2bs2(a.x, a.y); u.w[1] = f2bs2(a.z, a.w);
    u.w[2] = f2bs2(b.x, b.y); u.w[3] = f2bs2(b.z, b.w);
    return u.v;
}

// ---- prep: K,V fp32 -> bf16; V transposed to [bh][d][key] ----
__global__ __launch_bounds__(256) void prep_kv(const float* __restrict__ K,
                                               const float* __restrict__ V,
                                               short* __restrict__ Kb,
                                               short* __restrict__ Vtb) {
    __shared__ short T[64 * 80];
    const int bh = blockIdx.x >> 5;
    const int kt = blockIdx.x & 31;
    const int k0 = kt * 64;
    const int t  = threadIdx.x;
    const int row = t >> 2;          // key within tile
    const int cq  = (t & 3) * 16;    // d chunk

    const size_t base = (size_t)bh * S_LEN * D_DIM;
    {
        const float* kp = K + base + (size_t)(k0 + row) * D_DIM + cq;
        float4 a = ((const float4*)kp)[0], b = ((const float4*)kp)[1],
               c = ((const float4*)kp)[2], d = ((const float4*)kp)[3];
        short* op = Kb + base + (size_t)(k0 + row) * D_DIM + cq;
        *(bf16x8*)op       = cvt8(a, b);
        *(bf16x8*)(op + 8) = cvt8(c, d);
    }
    {
        const float* vp = V + base + (size_t)(k0 + row) * D_DIM + cq;
        float4 a = ((const float4*)vp)[0], b = ((const float4*)vp)[1],
               c = ((const float4*)vp)[2], d = ((const float4*)vp)[3];
        float vv[16] = {a.x,a.y,a.z,a.w, b.x,b.y,b.z,b.w,
                        c.x,c.y,c.z,c.w, d.x,d.y,d.z,d.w};
        #pragma unroll
        for (int i = 0; i < 16; ++i)
            T[(cq + i) * 80 + row] = f2bs(vv[i]);   // LDS transpose
    }
    __syncthreads();
    {
        const int d  = t >> 2;
        const int kc = (t & 3) * 16;
        short* op = Vtb + (size_t)bh * D_DIM * S_LEN + (size_t)d * S_LEN + k0 + kc;
        *(bf16x8*)op       = *(const bf16x8*)&T[d * 80 + kc];
        *(bf16x8*)(op + 8) = *(const bf16x8*)&T[d * 80 + kc + 8];
    }
}

// ---- mask -> 1 bit per col, u64 per 64 cols: Mp[(b*S+row)*32 + w] ----
__global__ __launch_bounds__(256) void mask_pack(const int* __restrict__ M,
                                                 u64* __restrict__ Mp) {
    const int lane = threadIdx.x & 63;
    const int wid  = (blockIdx.x * 256 + threadIdx.x) >> 6;
    const int nwaves = gridDim.x * 4;
    const int nwords = 2 * S_LEN * (S_LEN / 64);
    for (int w = wid; w < nwords; w += nwaves) {
        int v = M[(size_t)w * 64 + lane];
        u64 bits = __ballot(v != 0);
        if (lane == 0) Mp[w] = bits;
    }
}

// ---- main: barrier-free, K/V fragments direct from L2 ----
__global__ __launch_bounds__(256, 4) void sdpa_main(
    const float* __restrict__ Q, const short* __restrict__ Kb,
    const short* __restrict__ Vtb, const u64* __restrict__ Mp,
    float* __restrict__ Ctx, float* __restrict__ Attn)
{
    __shared__ short Pt[4 * 16 * 80];   // per-wave P round-trip, stride 80

    const int tid  = threadIdx.x;
    const int wave = tid >> 6;
    const int lane = tid & 63;
    const int quad = lane >> 4;
    const int l16  = lane & 15;

    const int bid = blockIdx.x;                    // 1024 = 32 bh x 32 qt
    const int bh  = ((bid >> 8) << 3) | (bid & 7); // same-bh blocks share bid%8 (XCD L2)
    const int qt  = (bid >> 3) & 31;
    const int b   = bh >> 4;
    const int qw  = qt * 64 + wave * 16;

    const size_t sd_off = (size_t)bh * S_LEN * D_DIM;
    const float* Qbh = Q + sd_off;
    const short* Kbh = Kb + sd_off;                       // [key][d] bf16
    const short* Vbh = Vtb + (size_t)bh * D_DIM * S_LEN;  // [d][key] bf16
    float* Cbh = Ctx + sd_off;
    float* Abh = Attn + (size_t)bh * S_LEN * S_LEN;

    // per-lane fragment base pointers:
    // K B-frag lane(quad,l16) reads K[k0+cc*16+l16][kc*32+quad*8 ..+8]
    const short* kfp = Kbh + (size_t)l16 * D_DIM + quad * 8;
    // V B-frag lane(quad,l16) reads Vt[dc*16+l16][k0+kc*32+quad*8 ..+8]
    const short* vfp = Vbh + (size_t)l16 * S_LEN + quad * 8;

    // Q A-frag; scale folds 1/sqrt(64) and log2e (exp(x)=exp2(x*log2e))
    bf16x8 qfrag[2];
    {
        const int qrow = qw + l16;
        const float s = 0.125f * LOG2E;
        #pragma unroll
        for (int kc = 0; kc < 2; ++kc) {
            const float* qp = Qbh + (size_t)qrow * D_DIM + kc * 32 + quad * 8;
            float4 a = ((const float4*)qp)[0], c = ((const float4*)qp)[1];
            a.x*=s; a.y*=s; a.z*=s; a.w*=s; c.x*=s; c.y*=s; c.z*=s; c.w*=s;
            qfrag[kc] = cvt8(a, c);
        }
    }

    const u64* mp = Mp + (size_t)(b * S_LEN + qw + quad * 4) * (S_LEN / 64);

    // ================= sweep 1: row sums =================
    float lacc[4] = {0.f, 0.f, 0.f, 0.f};
    for (int kt = 0; kt < 32; ++kt) {
        const int k0 = kt * 64;
        u64 mw[4];
        #pragma unroll
        for (int r = 0; r < 4; ++r) mw[r] = mp[r * 32 + kt];
        #pragma unroll
        for (int cc = 0; cc < 4; ++cc) {
            const short* kp = kfp + (size_t)(k0 + cc * 16) * D_DIM;
            f32x4 acc = {0.f, 0.f, 0.f, 0.f};
            acc = __builtin_amdgcn_mfma_f32_16x16x32_bf16(qfrag[0], *(const bf16x8*)kp,        acc, 0, 0, 0);
            acc = __builtin_amdgcn_mfma_f32_16x16x32_bf16(qfrag[1], *(const bf16x8*)(kp + 32), acc, 0, 0, 0);
            const int keyl = cc * 16 + l16;
            #pragma unroll
            for (int r = 0; r < 4; ++r) {
                float p = __builtin_amdgcn_exp2f(acc[r]);
                p = ((mw[r] >> keyl) & 1ull) ? 0.f : p;
                lacc[r] += p;
            }
        }
    }
    #pragma unroll
    for (int off = 1; off < 16; off <<= 1) {
        #pragma unroll
        for (int r = 0; r < 4; ++r) lacc[r] += __shfl_xor(lacc[r], off, 64);
    }
    float inv_l[4];
    #pragma unroll
    for (int r = 0; r < 4; ++r) inv_l[r] = 1.0f / lacc[r];

    // ================= sweep 2: attn write + PV =================
    f32x4 cacc[4];
    #pragma unroll
    for (int dc = 0; dc < 4; ++dc) cacc[dc] = (f32x4){0.f, 0.f, 0.f, 0.f};
    short* Pw = &Pt[wave * 16 * 80];

    for (int kt = 0; kt < 32; ++kt) {
        const int k0 = kt * 64;
        u64 mw[4];
        #pragma unroll
        for (int r = 0; r < 4; ++r) mw[r] = mp[r * 32 + kt];

        // prefetch V fragments for this tile (consumed after QK^T/exp phase)
        bf16x8 vfr[2][4];
        #pragma unroll
        for (int kc = 0; kc < 2; ++kc) {
            #pragma unroll
            for (int dc = 0; dc < 4; ++dc) {
                vfr[kc][dc] = *(const bf16x8*)(vfp + (size_t)dc * 16 * S_LEN + k0 + kc * 32);
            }
        }

        float* ap0 = Abh + (size_t)(qw + quad * 4) * S_LEN + k0;
        #pragma unroll
        for (int cc = 0; cc < 4; ++cc) {
            const short* kp = kfp + (size_t)(k0 + cc * 16) * D_DIM;
            f32x4 acc = {0.f, 0.f, 0.f, 0.f};
            acc = __builtin_amdgcn_mfma_f32_16x16x32_bf16(qfrag[0], *(const bf16x8*)kp,        acc, 0, 0, 0);
            acc = __builtin_amdgcn_mfma_f32_16x16x32_bf16(qfrag[1], *(const bf16x8*)(kp + 32), acc, 0, 0, 0);
            const int keyl = cc * 16 + l16;
            #pragma unroll
            for (int r = 0; r < 4; ++r) {
                float p = __builtin_amdgcn_exp2f(acc[r]);
                p = ((mw[r] >> keyl) & 1ull) ? 0.f : p;
                __builtin_nontemporal_store(p * inv_l[r], ap0 + (size_t)r * S_LEN + keyl);
                Pw[(quad * 4 + r) * 80 + keyl] = f2bs(p);   // unnormalized P
            }
        }
        // PV: wave-private Pt, in-wave lgkmcnt ordering suffices
        #pragma unroll
        for (int kc = 0; kc < 2; ++kc) {
            bf16x8 af = *(const bf16x8*)&Pw[l16 * 80 + kc * 32 + quad * 8];
            #pragma unroll
            for (int dc = 0; dc < 4; ++dc) {
                cacc[dc] = __builtin_amdgcn_mfma_f32_16x16x32_bf16(af, vfr[kc][dc], cacc[dc], 0, 0, 0);
            }
        }
    }

    #pragma unroll
    for (int dc = 0; dc < 4; ++dc) {
        #pragma unroll
        for (int r = 0; r < 4; ++r) {
            Cbh[(size_t)(qw + quad * 4 + r) * D_DIM + dc * 16 + l16] =
                cacc[dc][r] * inv_l[r];
        }
    }
}

extern "C" void kernel_launch(void* const* d_in, const int* in_sizes, int n_in,
                              void* d_out, int out_size, void* d_ws, size_t ws_size,
                              hipStream_t stream) {
    const float* Q    = (const float*)d_in[0];
    const float* K    = (const float*)d_in[1];
    const float* V    = (const float*)d_in[2];
    const int*   Mask = (const int*)d_in[3];

    float* Ctx  = (float*)d_out;
    float* Attn = (float*)d_out + (size_t)2 * 16 * 2048 * 64;

    short* Kb  = (short*)d_ws;                           // 8,388,608 B
    short* Vtb = (short*)((char*)d_ws + 8388608);        // 8,388,608 B
    u64*   Mp  = (u64*)((char*)d_ws + 16777216);         // 1,048,576 B

    prep_kv<<<dim3(1024), dim3(256), 0, stream>>>(K, V, Kb, Vtb);
    mask_pack<<<dim3(512), dim3(256), 0, stream>>>(Mask, Mp);
    sdpa_main<<<dim3(1024), dim3(256), 0, stream>>>(Q, Kb, Vtb, Mp, Ctx, Attn);
}

// Round 2
// 752.001 us; speedup vs baseline: 1.2148x; 1.2148x over previous
//
#include <hip/hip_runtime.h>
#include <hip/hip_bf16.h>

// SDPA, attention materialized. B=2 H=16 S=2048 D=64, fp32 in/out.
// Round 4: T3/T4 counted-vmcnt pipeline. K staged via global_load_lds into
// double-buffered XOR-swizzled LDS, ONE raw s_barrier per tile, manual
// s_waitcnt vmcnt(N) counted so NT attn stores are NEVER drained (they fly
// across barriers). V fragments are plain vector loads pinned in the top
// region by memory fences (round-1 lesson: unfenced "prefetch" gets sunk to
// the consumer; VGPR=52 proved it). Mask words prefetched one tile ahead so
// their wait never forces store retirement.
//
// vmcnt protocol (per-lane issue order, sweep2 steady state):
//   iter t:   TOP[ mp(t+1) x4, V(t) x8 ] WAIT vmcnt(28) BARRIER
//             STAGE[ K(t+1) gl2lds x2 ] fence QK[ NT stores x16 ] PV
//   newer-than-K(t) = stores(t-1) 16 + mp(t+1) 4 + V(t) 8 = 28.
//   sweep1 (no stores, no V): newer-than-K(t) = mp(t+1) 4 -> vmcnt(4).
//   sweep2 iter0 (K(0) staged by sweep1's stray prefetch): 4+8 = 12.
// Extra compiler-emitted vmem ops (e.g. spills) only lower the true
// "newer" count's floor -> fixed N over-waits, never under-waits.

#define S_LEN 2048
#define D_DIM 64
#define LOG2E 1.44269504088896340736f

typedef __attribute__((ext_vector_type(8))) short bf16x8;
typedef __attribute__((ext_vector_type(4))) float f32x4;
typedef unsigned long long u64;

#define FENCE() asm volatile("" ::: "memory")

__device__ __forceinline__ unsigned int f2bs2(float x, float y) {
    union { __hip_bfloat162 h; unsigned int u; } u;
    u.h = __float22bfloat162_rn(make_float2(x, y));
    return u.u;
}
__device__ __forceinline__ short f2bs(float f) {
    union { __hip_bfloat16 h; short s; } u;
    u.h = __float2bfloat16(f);
    return u.s;
}
__device__ __forceinline__ bf16x8 cvt8(float4 a, float4 b) {
    union { bf16x8 v; unsigned int w[4]; } u;
    u.w[0] = f2bs2(a.x, a.y); u.w[1] = f2bs2(a.z, a.w);
    u.w[2] = f2bs2(b.x, b.y); u.w[3] = f2bs2(b.z, b.w);
    return u.v;
}

__device__ __forceinline__ void gl2lds16(const short* g, short* l) {
    __builtin_amdgcn_global_load_lds(
        (const __attribute__((address_space(1))) unsigned int*)g,
        (__attribute__((address_space(3))) unsigned int*)l, 16, 0, 0);
}

// ---- prep: K,V fp32 -> bf16; V transposed to [bh][d][key] ----
__global__ __launch_bounds__(256) void prep_kv(const float* __restrict__ K,
                                               const float* __restrict__ V,
                                               short* __restrict__ Kb,
                                               short* __restrict__ Vtb) {
    __shared__ short T[64 * 80];
    const int bh = blockIdx.x >> 5;
    const int kt = blockIdx.x & 31;
    const int k0 = kt * 64;
    const int t  = threadIdx.x;
    const int row = t >> 2;          // key within tile
    const int cq  = (t & 3) * 16;    // d chunk

    const size_t base = (size_t)bh * S_LEN * D_DIM;
    {
        const float* kp = K + base + (size_t)(k0 + row) * D_DIM + cq;
        float4 a = ((const float4*)kp)[0], b = ((const float4*)kp)[1],
               c = ((const float4*)kp)[2], d = ((const float4*)kp)[3];
        short* op = Kb + base + (size_t)(k0 + row) * D_DIM + cq;
        *(bf16x8*)op       = cvt8(a, b);
        *(bf16x8*)(op + 8) = cvt8(c, d);
    }
    {
        const float* vp = V + base + (size_t)(k0 + row) * D_DIM + cq;
        float4 a = ((const float4*)vp)[0], b = ((const float4*)vp)[1],
               c = ((const float4*)vp)[2], d = ((const float4*)vp)[3];
        float vv[16] = {a.x,a.y,a.z,a.w, b.x,b.y,b.z,b.w,
                        c.x,c.y,c.z,c.w, d.x,d.y,d.z,d.w};
        #pragma unroll
        for (int i = 0; i < 16; ++i)
            T[(cq + i) * 80 + row] = f2bs(vv[i]);   // LDS transpose
    }
    __syncthreads();
    {
        const int d  = t >> 2;
        const int kc = (t & 3) * 16;
        short* op = Vtb + (size_t)bh * D_DIM * S_LEN + (size_t)d * S_LEN + k0 + kc;
        *(bf16x8*)op       = *(const bf16x8*)&T[d * 80 + kc];
        *(bf16x8*)(op + 8) = *(const bf16x8*)&T[d * 80 + kc + 8];
    }
}

// ---- mask -> 1 bit per col, u64 per 64 cols: Mp[(b*S+row)*32 + w] ----
__global__ __launch_bounds__(256) void mask_pack(const int* __restrict__ M,
                                                 u64* __restrict__ Mp) {
    const int lane = threadIdx.x & 63;
    const int wid  = (blockIdx.x * 256 + threadIdx.x) >> 6;
    const int nwaves = gridDim.x * 4;
    const int nwords = 2 * S_LEN * (S_LEN / 64);
    for (int w = wid; w < nwords; w += nwaves) {
        int v = M[(size_t)w * 64 + lane];
        u64 bits = __ballot(v != 0);
        if (lane == 0) Mp[w] = bits;
    }
}

// ---- main ----
__global__ __launch_bounds__(256, 4) void sdpa_main(
    const float* __restrict__ Q, const short* __restrict__ Kb,
    const short* __restrict__ Vtb, const u64* __restrict__ Mp,
    float* __restrict__ Ctx, float* __restrict__ Attn)
{
    // K double buffer, XOR-swizzled (gl2lds forces lane-contiguous dest):
    // element (row, chunk c of 8 shorts) lives at row*64 + (c^(row&7))*8.
    __shared__ short Kt[2][64 * 64];
    __shared__ short Pt[4 * 16 * 80];   // per-wave P round-trip, stride 80

    const int tid  = threadIdx.x;
    const int wave = tid >> 6;
    const int lane = tid & 63;
    const int quad = lane >> 4;
    const int l16  = lane & 15;

    const int bid = blockIdx.x;                    // 1024 = 32 bh x 32 qt
    const int bh  = ((bid >> 8) << 3) | (bid & 7); // same-bh blocks share bid%8 (XCD L2)
    const int qt  = (bid >> 3) & 31;
    const int b   = bh >> 4;
    const int qw  = qt * 64 + wave * 16;

    const size_t sd_off = (size_t)bh * S_LEN * D_DIM;
    const float* Qbh = Q + sd_off;
    const short* Kbh = Kb + sd_off;                       // [key][d] bf16
    const short* Vbh = Vtb + (size_t)bh * D_DIM * S_LEN;  // [d][key] bf16
    float* Cbh = Ctx + sd_off;
    float* Abh = Attn + (size_t)bh * S_LEN * S_LEN;

    // V B-frag lane(quad,l16) reads Vt[dc*16+l16][k0+kc*32+quad*8 ..+8]
    const short* vfp = Vbh + (size_t)l16 * S_LEN + quad * 8;

    // Q A-frag; scale folds 1/sqrt(64) and log2e (exp(x)=exp2(x*log2e))
    bf16x8 qfrag[2];
    {
        const int qrow = qw + l16;
        const float s = 0.125f * LOG2E;
        #pragma unroll
        for (int kc = 0; kc < 2; ++kc) {
            const float* qp = Qbh + (size_t)qrow * D_DIM + kc * 32 + quad * 8;
            float4 a = ((const float4*)qp)[0], c = ((const float4*)qp)[1];
            a.x*=s; a.y*=s; a.z*=s; a.w*=s; c.x*=s; c.y*=s; c.z*=s; c.w*=s;
            qfrag[kc] = cvt8(a, c);
        }
    }

    const u64* mp = Mp + (size_t)(b * S_LEN + qw + quad * 4) * (S_LEN / 64);

    u64 mw[4], mwn[4];
    float lacc[4] = {0.f, 0.f, 0.f, 0.f};

    // ---- sweep1 prologue: mask tile 0 + stage K tile 0 -> Kt[0] ----
    #pragma unroll
    for (int r = 0; r < 4; ++r) mw[r] = mp[r * 32];
    #pragma unroll
    for (int rd = 0; rd < 2; ++rd) {
        const int m = tid + rd * 256;
        const int row = m >> 3, sc = m & 7, c = sc ^ (row & 7);
        gl2lds16(Kbh + (size_t)row * D_DIM + c * 8, &Kt[0][m * 8]);
    }
    FENCE();

// ================= sweep 1 step: row sums, K dbuf, vmcnt(4) =================
#define S1_STEP(KT) do {                                                        \
    const int kt_ = (KT);                                                       \
    const int tn_ = (kt_ + 1) & 31; const int p_ = kt_ & 1;                     \
    _Pragma("unroll") for (int r = 0; r < 4; ++r) mwn[r] = mp[r * 32 + tn_];    \
    FENCE();                                                                    \
    asm volatile("s_waitcnt vmcnt(4)" ::: "memory");                            \
    __builtin_amdgcn_s_barrier();                                               \
    __builtin_amdgcn_sched_barrier(0);                                          \
    _Pragma("unroll") for (int rd = 0; rd < 2; ++rd) {                          \
        const int m_ = tid + rd * 256;                                          \
        const int row_ = m_ >> 3, sc_ = m_ & 7, c_ = sc_ ^ (row_ & 7);          \
        gl2lds16(Kbh + (size_t)(tn_ * 64 + row_) * D_DIM + c_ * 8,              \
                 &Kt[p_ ^ 1][m_ * 8]);                                          \
    }                                                                           \
    FENCE();                                                                    \
    __builtin_amdgcn_s_setprio(1);                                              \
    _Pragma("unroll") for (int cc = 0; cc < 4; ++cc) {                          \
        const int keyl_ = cc * 16 + l16;                                        \
        f32x4 acc_ = {0.f, 0.f, 0.f, 0.f};                                      \
        bf16x8 b0_ = *(const bf16x8*)&Kt[p_][keyl_ * 64 + ((quad) ^ (keyl_ & 7)) * 8];      \
        bf16x8 b1_ = *(const bf16x8*)&Kt[p_][keyl_ * 64 + ((4 + quad) ^ (keyl_ & 7)) * 8];  \
        acc_ = __builtin_amdgcn_mfma_f32_16x16x32_bf16(qfrag[0], b0_, acc_, 0, 0, 0);       \
        acc_ = __builtin_amdgcn_mfma_f32_16x16x32_bf16(qfrag[1], b1_, acc_, 0, 0, 0);       \
        _Pragma("unroll") for (int r = 0; r < 4; ++r) {                         \
            float pe_ = __builtin_amdgcn_exp2f(acc_[r]);                        \
            pe_ = ((mw[r] >> keyl_) & 1ull) ? 0.f : pe_;                        \
            lacc[r] += pe_;                                                     \
        }                                                                       \
    }                                                                           \
    __builtin_amdgcn_s_setprio(0);                                              \
    _Pragma("unroll") for (int r = 0; r < 4; ++r) mw[r] = mwn[r];               \
} while (0)

    #pragma unroll 1
    for (int kt = 0; kt < 32; ++kt) S1_STEP(kt);
    // sweep1's t=31 stray-prefetched K tile 0 into Kt[0] and mask tile 0
    // into mw -- exactly what sweep2 iter 0 needs.

    #pragma unroll
    for (int off = 1; off < 16; off <<= 1) {
        #pragma unroll
        for (int r = 0; r < 4; ++r) lacc[r] += __shfl_xor(lacc[r], off, 64);
    }
    float inv_l[4];
    #pragma unroll
    for (int r = 0; r < 4; ++r) inv_l[r] = 1.0f / lacc[r];

    f32x4 cacc[4];
    #pragma unroll
    for (int dc = 0; dc < 4; ++dc) cacc[dc] = (f32x4){0.f, 0.f, 0.f, 0.f};
    short* Pw = &Pt[wave * 16 * 80];

// ======== sweep 2 step: attn write + PV; V pinned in top region ========
#define S2_STEP(KT, WSTR) do {                                                  \
    const int kt_ = (KT); const int k0_ = kt_ * 64;                             \
    const int tn_ = (kt_ + 1) & 31; const int p_ = kt_ & 1;                     \
    _Pragma("unroll") for (int r = 0; r < 4; ++r) mwn[r] = mp[r * 32 + tn_];    \
    bf16x8 vfr[2][4];                                                           \
    _Pragma("unroll") for (int kc = 0; kc < 2; ++kc)                            \
        _Pragma("unroll") for (int dc = 0; dc < 4; ++dc)                        \
            vfr[kc][dc] = *(const bf16x8*)(vfp + (size_t)dc * 16 * S_LEN + k0_ + kc * 32);  \
    FENCE();                                                                    \
    asm volatile("s_waitcnt vmcnt(" WSTR ")" ::: "memory");                     \
    __builtin_amdgcn_s_barrier();                                               \
    __builtin_amdgcn_sched_barrier(0);                                          \
    _Pragma("unroll") for (int rd = 0; rd < 2; ++rd) {                          \
        const int m_ = tid + rd * 256;                                          \
        const int row_ = m_ >> 3, sc_ = m_ & 7, c_ = sc_ ^ (row_ & 7);          \
        gl2lds16(Kbh + (size_t)(tn_ * 64 + row_) * D_DIM + c_ * 8,              \
                 &Kt[p_ ^ 1][m_ * 8]);                                          \
    }                                                                           \
    FENCE();                                                                    \
    __builtin_amdgcn_s_setprio(1);                                              \
    float* ap0_ = Abh + (size_t)(qw + quad * 4) * S_LEN + k0_;                  \
    _Pragma("unroll") for (int cc = 0; cc < 4; ++cc) {                          \
        const int keyl_ = cc * 16 + l16;                                        \
        f32x4 acc_ = {0.f, 0.f, 0.f, 0.f};                                      \
        bf16x8 b0_ = *(const bf16x8*)&Kt[p_][keyl_ * 64 + ((quad) ^ (keyl_ & 7)) * 8];      \
        bf16x8 b1_ = *(const bf16x8*)&Kt[p_][keyl_ * 64 + ((4 + quad) ^ (keyl_ & 7)) * 8];  \
        acc_ = __builtin_amdgcn_mfma_f32_16x16x32_bf16(qfrag[0], b0_, acc_, 0, 0, 0);       \
        acc_ = __builtin_amdgcn_mfma_f32_16x16x32_bf16(qfrag[1], b1_, acc_, 0, 0, 0);       \
        _Pragma("unroll") for (int r = 0; r < 4; ++r) {                         \
            float pe_ = __builtin_amdgcn_exp2f(acc_[r]);                        \
            pe_ = ((mw[r] >> keyl_) & 1ull) ? 0.f : pe_;                        \
            __builtin_nontemporal_store(pe_ * inv_l[r], ap0_ + (size_t)r * S_LEN + keyl_);  \
            Pw[(quad * 4 + r) * 80 + keyl_] = f2bs(pe_);   /* unnormalized P */ \
        }                                                                       \
    }                                                                           \
    __builtin_amdgcn_s_setprio(0);                                              \
    FENCE();                                                                    \
    _Pragma("unroll") for (int kc = 0; kc < 2; ++kc) {                          \
        bf16x8 af_ = *(const bf16x8*)&Pw[l16 * 80 + kc * 32 + quad * 8];        \
        _Pragma("unroll") for (int dc = 0; dc < 4; ++dc)                        \
            cacc[dc] = __builtin_amdgcn_mfma_f32_16x16x32_bf16(af_, vfr[kc][dc], cacc[dc], 0, 0, 0); \
    }                                                                           \
    _Pragma("unroll") for (int r = 0; r < 4; ++r) mw[r] = mwn[r];               \
} while (0)

    S2_STEP(0, "12");   // peeled: only mp(1)x4 + V(0)x8 newer than K(0)
    #pragma unroll 1
    for (int kt = 1; kt < 32; ++kt) S2_STEP(kt, "28");

    #pragma unroll
    for (int dc = 0; dc < 4; ++dc) {
        #pragma unroll
        for (int r = 0; r < 4; ++r) {
            Cbh[(size_t)(qw + quad * 4 + r) * D_DIM + dc * 16 + l16] =
                cacc[dc][r] * inv_l[r];
        }
    }
}

extern "C" void kernel_launch(void* const* d_in, const int* in_sizes, int n_in,
                              void* d_out, int out_size, void* d_ws, size_t ws_size,
                              hipStream_t stream) {
    const float* Q    = (const float*)d_in[0];
    const float* K    = (const float*)d_in[1];
    const float* V    = (const float*)d_in[2];
    const int*   Mask = (const int*)d_in[3];

    float* Ctx  = (float*)d_out;
    float* Attn = (float*)d_out + (size_t)2 * 16 * 2048 * 64;

    short* Kb  = (short*)d_ws;                           // 8,388,608 B
    short* Vtb = (short*)((char*)d_ws + 8388608);        // 8,388,608 B
    u64*   Mp  = (u64*)((char*)d_ws + 16777216);         // 1,048,576 B

    prep_kv<<<dim3(1024), dim3(256), 0, stream>>>(K, V, Kb, Vtb);
    mask_pack<<<dim3(512), dim3(256), 0, stream>>>(Mask, Mp);
    sdpa_main<<<dim3(1024), dim3(256), 0, stream>>>(Q, Kb, Vtb, Mp, Ctx, Attn);
}

// Round 3
// 747.777 us; speedup vs baseline: 1.2216x; 1.0056x over previous
//
#include <hip/hip_runtime.h>
#include <hip/hip_bf16.h>

// SDPA, attention materialized. B=2 H=16 S=2048 D=64, fp32 in/out.
// Round 5: swapped QK^T (mfma(K,Q)) so each lane holds 4 CONSECUTIVE keys of
// one q-row (q = l16). Epilogue collapses: 4x dwordx4 NT attn stores per tile
// (was 16 scalar dwords), 1 mask u64/tile (was 4), scalar inv_l, normalized
// bf16 P -> Pt via 4x ds_write_b64 (was 16x b16), no Ctx renorm.
// Counted-vmcnt pipeline kept: K dbuf via global_load_lds, one raw s_barrier
// per tile, stores never drained.
//
// vmcnt protocol (per-lane issue order, sweep2 steady state):
//   iter t: TOP[ mp(t+1) x1, V(t) x8 ] WAIT vmcnt(13) BARRIER
//           STAGE[ K(t+1) x2 ] QK[ NT stores x4 ] PV
//   newer-than-K(t) = stores(t-1) 4 + mp(t+1) 1 + V(t) 8 = 13.
//   sweep1 (no stores/V): newer = mp(t+1) 1 -> vmcnt(1).
//   sweep2 iter0: mp 1 + V 8 = 9 -> vmcnt(9).

#define S_LEN 2048
#define D_DIM 64
#define LOG2E 1.44269504088896340736f

typedef __attribute__((ext_vector_type(8))) short bf16x8;
typedef __attribute__((ext_vector_type(4))) float f32x4;
typedef unsigned long long u64;

#define FENCE() asm volatile("" ::: "memory")

__device__ __forceinline__ unsigned int f2bs2(float x, float y) {
    union { __hip_bfloat162 h; unsigned int u; } u;
    u.h = __float22bfloat162_rn(make_float2(x, y));
    return u.u;
}
__device__ __forceinline__ short f2bs(float f) {
    union { __hip_bfloat16 h; short s; } u;
    u.h = __float2bfloat16(f);
    return u.s;
}
__device__ __forceinline__ bf16x8 cvt8(float4 a, float4 b) {
    union { bf16x8 v; unsigned int w[4]; } u;
    u.w[0] = f2bs2(a.x, a.y); u.w[1] = f2bs2(a.z, a.w);
    u.w[2] = f2bs2(b.x, b.y); u.w[3] = f2bs2(b.z, b.w);
    return u.v;
}

__device__ __forceinline__ void gl2lds16(const short* g, short* l) {
    __builtin_amdgcn_global_load_lds(
        (const __attribute__((address_space(1))) unsigned int*)g,
        (__attribute__((address_space(3))) unsigned int*)l, 16, 0, 0);
}

// ---- prep: K,V fp32 -> bf16; V transposed to [bh][d][key] ----
__global__ __launch_bounds__(256) void prep_kv(const float* __restrict__ K,
                                               const float* __restrict__ V,
                                               short* __restrict__ Kb,
                                               short* __restrict__ Vtb) {
    __shared__ short T[64 * 80];
    const int bh = blockIdx.x >> 5;
    const int kt = blockIdx.x & 31;
    const int k0 = kt * 64;
    const int t  = threadIdx.x;
    const int row = t >> 2;          // key within tile
    const int cq  = (t & 3) * 16;    // d chunk

    const size_t base = (size_t)bh * S_LEN * D_DIM;
    {
        const float* kp = K + base + (size_t)(k0 + row) * D_DIM + cq;
        float4 a = ((const float4*)kp)[0], b = ((const float4*)kp)[1],
               c = ((const float4*)kp)[2], d = ((const float4*)kp)[3];
        short* op = Kb + base + (size_t)(k0 + row) * D_DIM + cq;
        *(bf16x8*)op       = cvt8(a, b);
        *(bf16x8*)(op + 8) = cvt8(c, d);
    }
    {
        const float* vp = V + base + (size_t)(k0 + row) * D_DIM + cq;
        float4 a = ((const float4*)vp)[0], b = ((const float4*)vp)[1],
               c = ((const float4*)vp)[2], d = ((const float4*)vp)[3];
        float vv[16] = {a.x,a.y,a.z,a.w, b.x,b.y,b.z,b.w,
                        c.x,c.y,c.z,c.w, d.x,d.y,d.z,d.w};
        #pragma unroll
        for (int i = 0; i < 16; ++i)
            T[(cq + i) * 80 + row] = f2bs(vv[i]);   // LDS transpose
    }
    __syncthreads();
    {
        const int d  = t >> 2;
        const int kc = (t & 3) * 16;
        short* op = Vtb + (size_t)bh * D_DIM * S_LEN + (size_t)d * S_LEN + k0 + kc;
        *(bf16x8*)op       = *(const bf16x8*)&T[d * 80 + kc];
        *(bf16x8*)(op + 8) = *(const bf16x8*)&T[d * 80 + kc + 8];
    }
}

// ---- mask -> 1 bit per col, u64 per 64 cols: Mp[(b*S+row)*32 + w] ----
__global__ __launch_bounds__(256) void mask_pack(const int* __restrict__ M,
                                                 u64* __restrict__ Mp) {
    const int lane = threadIdx.x & 63;
    const int wid  = (blockIdx.x * 256 + threadIdx.x) >> 6;
    const int nwaves = gridDim.x * 4;
    const int nwords = 2 * S_LEN * (S_LEN / 64);
    for (int w = wid; w < nwords; w += nwaves) {
        int v = M[(size_t)w * 64 + lane];
        u64 bits = __ballot(v != 0);
        if (lane == 0) Mp[w] = bits;
    }
}

// ---- main ----
__global__ __launch_bounds__(256, 4) void sdpa_main(
    const float* __restrict__ Q, const short* __restrict__ Kb,
    const short* __restrict__ Vtb, const u64* __restrict__ Mp,
    float* __restrict__ Ctx, float* __restrict__ Attn)
{
    // K double buffer, XOR-swizzled (gl2lds forces lane-contiguous dest):
    // element (row, chunk c of 8 shorts) lives at row*64 + (c^(row&7))*8.
    __shared__ short Kt[2][64 * 64];
    __shared__ short Pt[4 * 16 * 80];   // per-wave normalized P, row-major [q][key], stride 80

    const int tid  = threadIdx.x;
    const int wave = tid >> 6;
    const int lane = tid & 63;
    const int quad = lane >> 4;
    const int l16  = lane & 15;

    const int bid = blockIdx.x;                    // 1024 = 32 bh x 32 qt
    const int bh  = ((bid >> 8) << 3) | (bid & 7); // same-bh blocks share bid%8 (XCD L2)
    const int qt  = (bid >> 3) & 31;
    const int b   = bh >> 4;
    const int qw  = qt * 64 + wave * 16;

    const size_t sd_off = (size_t)bh * S_LEN * D_DIM;
    const float* Qbh = Q + sd_off;
    const short* Kbh = Kb + sd_off;                       // [key][d] bf16
    const short* Vbh = Vtb + (size_t)bh * D_DIM * S_LEN;  // [d][key] bf16
    float* Cbh = Ctx + sd_off;
    float* Abh = Attn + (size_t)bh * S_LEN * S_LEN;

    // V B-frag lane(quad,l16) reads Vt[dc*16+l16][k0+kc*32+quad*8 ..+8]
    const short* vfp = Vbh + (size_t)l16 * S_LEN + quad * 8;

    // Q B-frag (swapped QK^T: Q is the second operand now, same data/layout);
    // scale folds 1/sqrt(64) and log2e (exp(x)=exp2(x*log2e))
    bf16x8 qfrag[2];
    {
        const int qrow = qw + l16;
        const float s = 0.125f * LOG2E;
        #pragma unroll
        for (int kc = 0; kc < 2; ++kc) {
            const float* qp = Qbh + (size_t)qrow * D_DIM + kc * 32 + quad * 8;
            float4 a = ((const float4*)qp)[0], c = ((const float4*)qp)[1];
            a.x*=s; a.y*=s; a.z*=s; a.w*=s; c.x*=s; c.y*=s; c.z*=s; c.w*=s;
            qfrag[kc] = cvt8(a, c);
        }
    }

    // per-lane mask row: q = qw + l16 (one u64 per 64-key tile)
    const u64* mp1 = Mp + (size_t)(b * S_LEN + qw + l16) * (S_LEN / 64);

    u64 mw, mwn;
    float lacc = 0.f;

    // ---- sweep1 prologue: mask tile 0 + stage K tile 0 -> Kt[0] ----
    mw = mp1[0];
    #pragma unroll
    for (int rd = 0; rd < 2; ++rd) {
        const int m = tid + rd * 256;
        const int row = m >> 3, sc = m & 7, c = sc ^ (row & 7);
        gl2lds16(Kbh + (size_t)row * D_DIM + c * 8, &Kt[0][m * 8]);
    }
    FENCE();

// ========= sweep 1 step: row sums (keys lane-local), vmcnt(1) =========
#define S1_STEP(KT) do {                                                        \
    const int kt_ = (KT);                                                       \
    const int tn_ = (kt_ + 1) & 31; const int p_ = kt_ & 1;                     \
    mwn = mp1[tn_];                                                             \
    FENCE();                                                                    \
    asm volatile("s_waitcnt vmcnt(1)" ::: "memory");                            \
    __builtin_amdgcn_s_barrier();                                               \
    __builtin_amdgcn_sched_barrier(0);                                          \
    _Pragma("unroll") for (int rd = 0; rd < 2; ++rd) {                          \
        const int m_ = tid + rd * 256;                                          \
        const int row_ = m_ >> 3, sc_ = m_ & 7, c_ = sc_ ^ (row_ & 7);          \
        gl2lds16(Kbh + (size_t)(tn_ * 64 + row_) * D_DIM + c_ * 8,              \
                 &Kt[p_ ^ 1][m_ * 8]);                                          \
    }                                                                           \
    FENCE();                                                                    \
    __builtin_amdgcn_s_setprio(1);                                              \
    _Pragma("unroll") for (int cc = 0; cc < 4; ++cc) {                          \
        const int keyl_ = cc * 16 + l16;                                        \
        f32x4 acc_ = {0.f, 0.f, 0.f, 0.f};                                      \
        bf16x8 k0f_ = *(const bf16x8*)&Kt[p_][keyl_ * 64 + ((quad) ^ (keyl_ & 7)) * 8];     \
        bf16x8 k1f_ = *(const bf16x8*)&Kt[p_][keyl_ * 64 + ((4 + quad) ^ (keyl_ & 7)) * 8]; \
        acc_ = __builtin_amdgcn_mfma_f32_16x16x32_bf16(k0f_, qfrag[0], acc_, 0, 0, 0);      \
        acc_ = __builtin_amdgcn_mfma_f32_16x16x32_bf16(k1f_, qfrag[1], acc_, 0, 0, 0);      \
        const unsigned bits_ = (unsigned)(mw >> (cc * 16 + quad * 4));          \
        _Pragma("unroll") for (int r = 0; r < 4; ++r) {                         \
            float pe_ = __builtin_amdgcn_exp2f(acc_[r]);                        \
            pe_ = ((bits_ >> r) & 1u) ? 0.f : pe_;                              \
            lacc += pe_;                                                        \
        }                                                                       \
    }                                                                           \
    __builtin_amdgcn_s_setprio(0);                                              \
    mw = mwn;                                                                   \
} while (0)

    #pragma unroll 1
    for (int kt = 0; kt < 32; ++kt) S1_STEP(kt);
    // sweep1's t=31 stray-prefetched K tile 0 into Kt[0]; mw wrapped to tile 0.

    // combine the 4 quads (each lane summed its 16 of 64 keys per tile)
    lacc += __shfl_xor(lacc, 16, 64);
    lacc += __shfl_xor(lacc, 32, 64);
    const float inv_l = 1.0f / lacc;    // for q-row = qw + l16

    f32x4 cacc[4];
    #pragma unroll
    for (int dc = 0; dc < 4; ++dc) cacc[dc] = (f32x4){0.f, 0.f, 0.f, 0.f};
    short* Pw = &Pt[wave * 16 * 80];

// ==== sweep 2 step: x4 attn store + PV; V pinned in top region ====
#define S2_STEP(KT, WSTR) do {                                                  \
    const int kt_ = (KT); const int k0_ = kt_ * 64;                             \
    const int tn_ = (kt_ + 1) & 31; const int p_ = kt_ & 1;                     \
    mwn = mp1[tn_];                                                             \
    bf16x8 vfr[2][4];                                                           \
    _Pragma("unroll") for (int kc = 0; kc < 2; ++kc)                            \
        _Pragma("unroll") for (int dc = 0; dc < 4; ++dc)                        \
            vfr[kc][dc] = *(const bf16x8*)(vfp + (size_t)dc * 16 * S_LEN + k0_ + kc * 32);  \
    FENCE();                                                                    \
    asm volatile("s_waitcnt vmcnt(" WSTR ")" ::: "memory");                     \
    __builtin_amdgcn_s_barrier();                                               \
    __builtin_amdgcn_sched_barrier(0);                                          \
    _Pragma("unroll") for (int rd = 0; rd < 2; ++rd) {                          \
        const int m_ = tid + rd * 256;                                          \
        const int row_ = m_ >> 3, sc_ = m_ & 7, c_ = sc_ ^ (row_ & 7);          \
        gl2lds16(Kbh + (size_t)(tn_ * 64 + row_) * D_DIM + c_ * 8,              \
                 &Kt[p_ ^ 1][m_ * 8]);                                          \
    }                                                                           \
    FENCE();                                                                    \
    __builtin_amdgcn_s_setprio(1);                                              \
    float* ap_ = Abh + (size_t)(qw + l16) * S_LEN + k0_ + quad * 4;             \
    _Pragma("unroll") for (int cc = 0; cc < 4; ++cc) {                          \
        const int keyl_ = cc * 16 + l16;                                        \
        f32x4 acc_ = {0.f, 0.f, 0.f, 0.f};                                      \
        bf16x8 k0f_ = *(const bf16x8*)&Kt[p_][keyl_ * 64 + ((quad) ^ (keyl_ & 7)) * 8];     \
        bf16x8 k1f_ = *(const bf16x8*)&Kt[p_][keyl_ * 64 + ((4 + quad) ^ (keyl_ & 7)) * 8]; \
        acc_ = __builtin_amdgcn_mfma_f32_16x16x32_bf16(k0f_, qfrag[0], acc_, 0, 0, 0);      \
        acc_ = __builtin_amdgcn_mfma_f32_16x16x32_bf16(k1f_, qfrag[1], acc_, 0, 0, 0);      \
        const unsigned bits_ = (unsigned)(mw >> (cc * 16 + quad * 4));          \
        f32x4 pn_;                                                              \
        _Pragma("unroll") for (int r = 0; r < 4; ++r) {                         \
            float pe_ = __builtin_amdgcn_exp2f(acc_[r]);                        \
            pe_ = ((bits_ >> r) & 1u) ? 0.f : pe_;                              \
            pn_[r] = pe_ * inv_l;      /* normalized */                         \
        }                                                                       \
        __builtin_nontemporal_store(pn_, (f32x4*)(ap_ + cc * 16));              \
        /* normalized bf16 P -> Pt[q=l16][key=cc*16+quad*4 ..+3], b64 write */  \
        union { unsigned w[2]; u64 d; } pk_;                                    \
        pk_.w[0] = f2bs2(pn_[0], pn_[1]); pk_.w[1] = f2bs2(pn_[2], pn_[3]);     \
        *(u64*)&Pw[l16 * 80 + cc * 16 + quad * 4] = pk_.d;                      \
    }                                                                           \
    __builtin_amdgcn_s_setprio(0);                                              \
    FENCE();                                                                    \
    _Pragma("unroll") for (int kc = 0; kc < 2; ++kc) {                          \
        bf16x8 af_ = *(const bf16x8*)&Pw[l16 * 80 + kc * 32 + quad * 8];        \
        _Pragma("unroll") for (int dc = 0; dc < 4; ++dc)                        \
            cacc[dc] = __builtin_amdgcn_mfma_f32_16x16x32_bf16(af_, vfr[kc][dc], cacc[dc], 0, 0, 0); \
    }                                                                           \
    mw = mwn;                                                                   \
} while (0)

    S2_STEP(0, "9");    // peeled: only mp(1)x1 + V(0)x8 newer than K(0)
    #pragma unroll 1
    for (int kt = 1; kt < 32; ++kt) S2_STEP(kt, "13");

    // P was normalized -> Ctx is cacc directly
    #pragma unroll
    for (int dc = 0; dc < 4; ++dc) {
        #pragma unroll
        for (int r = 0; r < 4; ++r) {
            Cbh[(size_t)(qw + quad * 4 + r) * D_DIM + dc * 16 + l16] = cacc[dc][r];
        }
    }
}

extern "C" void kernel_launch(void* const* d_in, const int* in_sizes, int n_in,
                              void* d_out, int out_size, void* d_ws, size_t ws_size,
                              hipStream_t stream) {
    const float* Q    = (const float*)d_in[0];
    const float* K    = (const float*)d_in[1];
    const float* V    = (const float*)d_in[2];
    const int*   Mask = (const int*)d_in[3];

    float* Ctx  = (float*)d_out;
    float* Attn = (float*)d_out + (size_t)2 * 16 * 2048 * 64;

    short* Kb  = (short*)d_ws;                           // 8,388,608 B
    short* Vtb = (short*)((char*)d_ws + 8388608);        // 8,388,608 B
    u64*   Mp  = (u64*)((char*)d_ws + 16777216);         // 1,048,576 B

    prep_kv<<<dim3(1024), dim3(256), 0, stream>>>(K, V, Kb, Vtb);
    mask_pack<<<dim3(512), dim3(256), 0, stream>>>(Mask, Mp);
    sdpa_main<<<dim3(1024), dim3(256), 0, stream>>>(Q, Kb, Vtb, Mp, Ctx, Attn);
}